// Round 1
// baseline (841.045 us; speedup 1.0000x reference)
//
#include <hip/hip_runtime.h>
#include <hip/hip_bf16.h>
#include <cstdint>

#define NPTS 4096
#define NB 8
#define KNN 20

__device__ __forceinline__ float lrelu(float x) { return x >= 0.0f ? x : 0.2f * x; }

// monotone float<->uint mapping for atomicMax on floats
__device__ __forceinline__ uint32_t enc_f32(float f) {
    uint32_t u = __float_as_uint(f);
    return (u & 0x80000000u) ? ~u : (u | 0x80000000u);
}
__device__ __forceinline__ float dec_f32(uint32_t u) {
    return (u & 0x80000000u) ? __uint_as_float(u ^ 0x80000000u) : __uint_as_float(~u);
}

// ---------------------------------------------------------------------------
// K1: fused kNN (top-20 by smallest sq-dist, ties -> smaller index) + EdgeConv
//     (6->64) + max over k.  One wave per query row, 16 rows per block.
// ---------------------------------------------------------------------------
__global__ __launch_bounds__(256) void k1_knn_edge(
        const float* __restrict__ x,
        const float* __restrict__ W0, const float* __restrict__ b0,
        const float* __restrict__ s0, const float* __restrict__ t0,
        float* __restrict__ H0)
{
    __shared__ float4 pts[NPTS];          // x,y,z,xx   (64 KB)
    __shared__ float sW0[64 * 6];
    __shared__ float sB[64], sS[64], sT[64];

    const int blk = blockIdx.x;
    const int b = blk >> 8;               // 256 blocks per batch
    const int rowbase = (blk & 255) << 4; // 16 rows per block
    const int t = threadIdx.x;
    const int lane = t & 63;
    const int w = t >> 6;

    const float* xb = x + (size_t)b * (NPTS * 3);
    for (int i = t; i < NPTS; i += 256) {
        float x0 = xb[3 * i], x1 = xb[3 * i + 1], x2 = xb[3 * i + 2];
        // xx exactly as reference: (x0*x0 + x1*x1) + x2*x2, no fma
        float xx = __fadd_rn(__fadd_rn(__fmul_rn(x0, x0), __fmul_rn(x1, x1)),
                             __fmul_rn(x2, x2));
        pts[i] = make_float4(x0, x1, x2, xx);
    }
    if (t < 64) {
        #pragma unroll
        for (int c = 0; c < 6; c++) sW0[t * 6 + c] = W0[t * 6 + c];
        sB[t] = b0[t]; sS[t] = s0[t]; sT[t] = t0[t];
    }
    __syncthreads();

    // per-lane output channel o = lane
    const float wa0 = sW0[lane * 6 + 0], wa1 = sW0[lane * 6 + 1], wa2 = sW0[lane * 6 + 2];
    const float wd0 = sW0[lane * 6 + 3] - wa0;
    const float wd1 = sW0[lane * 6 + 4] - wa1;
    const float wd2 = sW0[lane * 6 + 5] - wa2;

    for (int it = 0; it < 4; it++) {
        const int r = rowbase + w * 4 + it;
        const float4 q = pts[r];
        const float negqxx = -q.w;

        // per-lane sorted top-2 of neg_sq_dist s (descending s, ascending idx).
        // candidates arrive in increasing index within a lane, so strict '>'
        // keeps earlier index on exact ties (matches lax.top_k).
        float l0s = -INFINITY, l1s = -INFINITY;
        int   l0i = 0x7FFFFFFF, l1i = 0x7FFFFFFF;
        #pragma unroll 8
        for (int j = 0; j < 64; j++) {
            const int m = (j << 6) | lane;
            const float4 p = pts[m];
            float dot = __fadd_rn(__fadd_rn(__fmul_rn(q.x, p.x), __fmul_rn(q.y, p.y)),
                                  __fmul_rn(q.z, p.z));
            float inner = __fmul_rn(-2.0f, dot);
            float s = __fsub_rn(__fsub_rn(negqxx, inner), p.w);
            bool g0 = s > l0s;
            bool g1 = s > l1s;
            l1s = g0 ? l0s : (g1 ? s : l1s);
            l1i = g0 ? l0i : (g1 ? m : l1i);
            l0s = g0 ? s : l0s;
            l0i = g0 ? m : l0i;
        }

        float hs = l0s; int hi = l0i;   // lane head = best remaining
        int cnt = 0;                    // pops from this lane so far
        float mmax = -INFINITY;         // max over selected nbrs of W0a . p

        for (int rd = 0; rd < KNN; rd++) {
            // wave argmax of (s, -idx): butterfly, all lanes converge
            float bs = hs; int bi = hi;
            #pragma unroll
            for (int off = 32; off >= 1; off >>= 1) {
                float os = __shfl_xor(bs, off);
                int   oi = __shfl_xor(bi, off);
                bool take = (os > bs) || (os == bs && oi < bi);
                bs = take ? os : bs;
                bi = take ? oi : bi;
            }
            // EdgeConv accumulate (all lanes, o = lane), LDS broadcast read
            {
                const float4 p = pts[bi];
                float dotp = wa0 * p.x + wa1 * p.y + wa2 * p.z;
                mmax = fmaxf(mmax, dotp);
            }
            // owner lane advances its head
            if (hi == bi) {
                cnt++;
                const float ls = hs; const int li = hi;
                if (cnt == 1) {
                    hs = l1s; hi = l1i;
                } else {
                    // rare rescan: best candidate strictly worse than (ls,li)
                    float ns = -INFINITY; int ni = 0x7FFFFFFF;
                    for (int j = 0; j < 64; j++) {
                        const int m = (j << 6) | lane;
                        const float4 p2 = pts[m];
                        float dot2 = __fadd_rn(__fadd_rn(__fmul_rn(q.x, p2.x),
                                                         __fmul_rn(q.y, p2.y)),
                                               __fmul_rn(q.z, p2.z));
                        float s2 = __fsub_rn(__fsub_rn(negqxx, __fmul_rn(-2.0f, dot2)), p2.w);
                        bool worse = (s2 < ls) || (s2 == ls && m > li);
                        bool bett  = (s2 > ns) || (s2 == ns && m < ni);
                        if (worse && bett) { ns = s2; ni = m; }
                    }
                    hs = ns; hi = ni;
                }
            }
        }

        // conv = max_k(W0a.p_k) + (W0b-W0a).q ; then (conv + b)*s + t ; lrelu.
        // s0>0 and lrelu monotone => max commutes past affine+activation.
        float cterm = wd0 * q.x + wd1 * q.y + wd2 * q.z;
        float z = (mmax + cterm + sB[lane]) * sS[lane] + sT[lane];
        H0[((size_t)(b * NPTS) + r) * 64 + lane] = lrelu(z);
    }
}

// ---------------------------------------------------------------------------
// K2: pconv chain 64->64->128->128 + max over points, fused.  32-pt tiles.
// ---------------------------------------------------------------------------
__global__ __launch_bounds__(256) void k2_mlp(
        const float* __restrict__ H0,
        const float* __restrict__ W1, const float* __restrict__ b1,
        const float* __restrict__ s1, const float* __restrict__ t1,
        const float* __restrict__ W2, const float* __restrict__ b2,
        const float* __restrict__ s2, const float* __restrict__ t2,
        const float* __restrict__ W3, const float* __restrict__ b3,
        const float* __restrict__ s3, const float* __restrict__ t3,
        uint32_t* __restrict__ gmax)
{
    __shared__ float sW1[64 * 68];    // W1^T [c][o], stride 68
    __shared__ float sW2[64 * 132];   // W2^T [c][o], stride 132
    __shared__ float sW3[128 * 132];  // W3^T [c][o], stride 132
    __shared__ float h0t[32 * 65];
    __shared__ float h1t[32 * 65];
    __shared__ float h2t[32 * 129];
    __shared__ uint32_t bmax[128];

    const int t = threadIdx.x;
    const int blk = blockIdx.x;
    const int b = blk >> 7;               // 128 blocks per batch
    const int pbase = (blk & 127) * 32;

    for (int i = t; i < 64 * 64; i += 256)  { int o = i >> 6, c = i & 63;  sW1[c * 68 + o]  = W1[i]; }
    for (int i = t; i < 128 * 64; i += 256) { int o = i >> 6, c = i & 63;  sW2[c * 132 + o] = W2[i]; }
    for (int i = t; i < 128 * 128; i += 256){ int o = i >> 7, c = i & 127; sW3[c * 132 + o] = W3[i]; }
    {
        const float* src = &H0[((size_t)(b * NPTS) + pbase) * 64];
        for (int i = t; i < 32 * 64; i += 256) { int p = i >> 6, c = i & 63; h0t[p * 65 + c] = src[i]; }
    }
    if (t < 128) bmax[t] = 0u;
    __syncthreads();

    const int p = t >> 3;   // 0..31
    const int g = t & 7;

    // L1: 64 -> 64, thread computes o = g*8 + [0..8)
    {
        float a[8];
        #pragma unroll
        for (int i = 0; i < 8; i++) a[i] = 0.f;
        const float* hrow = &h0t[p * 65];
        for (int c = 0; c < 64; c++) {
            float hv = hrow[c];
            const float4* wr = (const float4*)&sW1[c * 68 + g * 8];
            float4 w0v = wr[0], w1v = wr[1];
            a[0] += hv * w0v.x; a[1] += hv * w0v.y; a[2] += hv * w0v.z; a[3] += hv * w0v.w;
            a[4] += hv * w1v.x; a[5] += hv * w1v.y; a[6] += hv * w1v.z; a[7] += hv * w1v.w;
        }
        #pragma unroll
        for (int i = 0; i < 8; i++) {
            int o = g * 8 + i;
            float z = (a[i] + b1[o]) * s1[o] + t1[o];
            h1t[p * 65 + o] = lrelu(z);
        }
    }
    __syncthreads();

    // L2: 64 -> 128, thread computes o = g*16 + [0..16)
    {
        float a[16];
        #pragma unroll
        for (int i = 0; i < 16; i++) a[i] = 0.f;
        const float* hrow = &h1t[p * 65];
        for (int c = 0; c < 64; c++) {
            float hv = hrow[c];
            const float4* wr = (const float4*)&sW2[c * 132 + g * 16];
            #pragma unroll
            for (int v = 0; v < 4; v++) {
                float4 wv = wr[v];
                a[v * 4 + 0] += hv * wv.x; a[v * 4 + 1] += hv * wv.y;
                a[v * 4 + 2] += hv * wv.z; a[v * 4 + 3] += hv * wv.w;
            }
        }
        #pragma unroll
        for (int i = 0; i < 16; i++) {
            int o = g * 16 + i;
            float z = (a[i] + b2[o]) * s2[o] + t2[o];
            h2t[p * 129 + o] = lrelu(z);
        }
    }
    __syncthreads();

    // L3: 128 -> 128 + block max
    {
        float a[16];
        #pragma unroll
        for (int i = 0; i < 16; i++) a[i] = 0.f;
        const float* hrow = &h2t[p * 129];
        for (int c = 0; c < 128; c++) {
            float hv = hrow[c];
            const float4* wr = (const float4*)&sW3[c * 132 + g * 16];
            #pragma unroll
            for (int v = 0; v < 4; v++) {
                float4 wv = wr[v];
                a[v * 4 + 0] += hv * wv.x; a[v * 4 + 1] += hv * wv.y;
                a[v * 4 + 2] += hv * wv.z; a[v * 4 + 3] += hv * wv.w;
            }
        }
        #pragma unroll
        for (int i = 0; i < 16; i++) {
            int o = g * 16 + i;
            float z = (a[i] + b3[o]) * s3[o] + t3[o];
            atomicMax(&bmax[o], enc_f32(lrelu(z)));
        }
    }
    __syncthreads();
    if (t < 128) atomicMax(&gmax[b * 128 + t], bmax[t]);
}

// ---------------------------------------------------------------------------
// K3: head 128 -> 512 (affine+lrelu) -> 1024.  One block per batch.
// ---------------------------------------------------------------------------
__global__ __launch_bounds__(256) void k3_head(
        const uint32_t* __restrict__ gmax,
        const float* __restrict__ W4, const float* __restrict__ b4,
        const float* __restrict__ s4, const float* __restrict__ t4,
        const float* __restrict__ W5, const float* __restrict__ b5,
        float* __restrict__ out)
{
    __shared__ float sIn[128];
    __shared__ float sH4[512];
    const int t = threadIdx.x;
    const int b = blockIdx.x;

    if (t < 128) sIn[t] = dec_f32(gmax[b * 128 + t]);
    __syncthreads();

    #pragma unroll
    for (int rep = 0; rep < 2; rep++) {
        int o = t + rep * 256;
        float acc = 0.f;
        const float* wr = &W4[(size_t)o * 128];
        for (int c = 0; c < 128; c++) acc += sIn[c] * wr[c];
        float z = (acc + b4[o]) * s4[o] + t4[o];
        sH4[o] = lrelu(z);
    }
    __syncthreads();

    #pragma unroll
    for (int rep = 0; rep < 4; rep++) {
        int o = t + rep * 256;
        float acc = 0.f;
        const float* wr = &W5[(size_t)o * 512];
        for (int c = 0; c < 512; c++) acc += sH4[c] * wr[c];
        out[(size_t)b * 1024 + o] = acc + b5[o];
    }
}

// ---------------------------------------------------------------------------
extern "C" void kernel_launch(void* const* d_in, const int* in_sizes, int n_in,
                              void* d_out, int out_size, void* d_ws, size_t ws_size,
                              hipStream_t stream) {
    (void)in_sizes; (void)n_in; (void)out_size; (void)ws_size;
    const float* x  = (const float*)d_in[0];
    const float* W0 = (const float*)d_in[1];
    const float* b0 = (const float*)d_in[2];
    const float* s0 = (const float*)d_in[3];
    const float* t0 = (const float*)d_in[4];
    const float* W1 = (const float*)d_in[5];
    const float* b1 = (const float*)d_in[6];
    const float* s1 = (const float*)d_in[7];
    const float* t1 = (const float*)d_in[8];
    const float* W2 = (const float*)d_in[9];
    const float* b2 = (const float*)d_in[10];
    const float* s2 = (const float*)d_in[11];
    const float* t2 = (const float*)d_in[12];
    const float* W3 = (const float*)d_in[13];
    const float* b3 = (const float*)d_in[14];
    const float* s3 = (const float*)d_in[15];
    const float* t3 = (const float*)d_in[16];
    const float* W4 = (const float*)d_in[17];
    const float* b4 = (const float*)d_in[18];
    const float* s4 = (const float*)d_in[19];
    const float* t4 = (const float*)d_in[20];
    const float* W5 = (const float*)d_in[21];
    const float* b5 = (const float*)d_in[22];

    float* H0 = (float*)d_ws;                                  // [8][4096][64] f32 = 8 MB
    uint32_t* gmax = (uint32_t*)((char*)d_ws + (size_t)NB * NPTS * 64 * 4);  // [8][128] u32

    hipMemsetAsync(gmax, 0, NB * 128 * sizeof(uint32_t), stream);  // enc(-inf) < any enc

    k1_knn_edge<<<dim3(2048), dim3(256), 0, stream>>>(x, W0, b0, s0, t0, H0);
    k2_mlp<<<dim3(1024), dim3(256), 0, stream>>>(H0, W1, b1, s1, t1,
                                                 W2, b2, s2, t2,
                                                 W3, b3, s3, t3, gmax);
    k3_head<<<dim3(8), dim3(256), 0, stream>>>(gmax, W4, b4, s4, t4, W5, b5,
                                               (float*)d_out);
}

// Round 2
// 237.366 us; speedup vs baseline: 3.5432x; 3.5432x over previous
//
#include <hip/hip_runtime.h>
#include <hip/hip_bf16.h>
#include <cstdint>

#define NPTS 4096
#define NB 8
#define KNN 20

__device__ __forceinline__ float lrelu(float x) { return x >= 0.0f ? x : 0.2f * x; }

// monotone float<->uint mapping for atomicMax on floats
__device__ __forceinline__ uint32_t enc_f32(float f) {
    uint32_t u = __float_as_uint(f);
    return (u & 0x80000000u) ? ~u : (u | 0x80000000u);
}
__device__ __forceinline__ float dec_f32(uint32_t u) {
    return (u & 0x80000000u) ? __uint_as_float(u ^ 0x80000000u) : __uint_as_float(~u);
}

// ---------------------------------------------------------------------------
// K1: fused kNN (top-20 smallest sq-dist, ties -> smaller index) + EdgeConv
//     (6->64) + max over k.  512-thread blocks (8 waves), each wave processes
//     4 rows interleaved (ILP hides shfl/LDS latency).  Per-lane top-4.
// ---------------------------------------------------------------------------
__global__ __launch_bounds__(512, 4) void k1_knn_edge(
        const float* __restrict__ x,
        const float* __restrict__ W0, const float* __restrict__ b0,
        const float* __restrict__ s0, const float* __restrict__ t0,
        float* __restrict__ H0)
{
    __shared__ float4 pts[NPTS];          // x,y,z,xx   (64 KB)
    __shared__ float sW0[64 * 6];
    __shared__ float sB[64], sS[64], sT[64];

    const int blk = blockIdx.x;
    const int b = blk >> 7;               // 128 blocks per batch
    const int rowbase = (blk & 127) << 5; // 32 rows per block
    const int t = threadIdx.x;
    const int lane = t & 63;
    const int w = t >> 6;                 // wave 0..7

    const float* xb = x + (size_t)b * (NPTS * 3);
    for (int i = t; i < NPTS; i += 512) {
        float x0 = xb[3 * i], x1 = xb[3 * i + 1], x2 = xb[3 * i + 2];
        // xx exactly as reference: (x0*x0 + x1*x1) + x2*x2, no fma
        float xx = __fadd_rn(__fadd_rn(__fmul_rn(x0, x0), __fmul_rn(x1, x1)),
                             __fmul_rn(x2, x2));
        pts[i] = make_float4(x0, x1, x2, xx);
    }
    if (t < 64) {
        #pragma unroll
        for (int c = 0; c < 6; c++) sW0[t * 6 + c] = W0[t * 6 + c];
        sB[t] = b0[t]; sS[t] = s0[t]; sT[t] = t0[t];
    }
    __syncthreads();

    // per-lane output channel o = lane
    const float wa0 = sW0[lane * 6 + 0], wa1 = sW0[lane * 6 + 1], wa2 = sW0[lane * 6 + 2];
    const float wd0 = sW0[lane * 6 + 3] - wa0;
    const float wd1 = sW0[lane * 6 + 4] - wa1;
    const float wd2 = sW0[lane * 6 + 5] - wa2;

    const int r0 = rowbase + w * 4;
    float4 q[4];
    float nq[4];
    #pragma unroll
    for (int rr = 0; rr < 4; rr++) { q[rr] = pts[r0 + rr]; nq[rr] = -q[rr].w; }

    // per-lane sorted top-4 (descending s; strict '>' keeps earlier index on
    // ties since candidates arrive in increasing index within a lane)
    float l0s[4], l1s[4], l2s[4], l3s[4];
    int   l0i[4], l1i[4], l2i[4], l3i[4];
    #pragma unroll
    for (int rr = 0; rr < 4; rr++) {
        l0s[rr] = l1s[rr] = l2s[rr] = l3s[rr] = -INFINITY;
        l0i[rr] = l1i[rr] = l2i[rr] = l3i[rr] = 0x7FFFFFFF;
    }

    // ---- scan: one candidate read shared by 4 rows ----
    for (int j = 0; j < 64; j++) {
        const int m = (j << 6) | lane;
        const float4 p = pts[m];
        #pragma unroll
        for (int rr = 0; rr < 4; rr++) {
            float dot = __fadd_rn(__fadd_rn(__fmul_rn(q[rr].x, p.x),
                                            __fmul_rn(q[rr].y, p.y)),
                                  __fmul_rn(q[rr].z, p.z));
            float s = __fsub_rn(__fsub_rn(nq[rr], __fmul_rn(-2.0f, dot)), p.w);
            bool g0 = s > l0s[rr], g1 = s > l1s[rr], g2 = s > l2s[rr], g3 = s > l3s[rr];
            l3s[rr] = g2 ? l2s[rr] : (g3 ? s : l3s[rr]);
            l3i[rr] = g2 ? l2i[rr] : (g3 ? m : l3i[rr]);
            l2s[rr] = g1 ? l1s[rr] : (g2 ? s : l2s[rr]);
            l2i[rr] = g1 ? l1i[rr] : (g2 ? m : l2i[rr]);
            l1s[rr] = g0 ? l0s[rr] : (g1 ? s : l1s[rr]);
            l1i[rr] = g0 ? l0i[rr] : (g1 ? m : l1i[rr]);
            l0s[rr] = g0 ? s : l0s[rr];
            l0i[rr] = g0 ? m : l0i[rr];
        }
    }

    // ---- merge: 20 rounds of wave argmax, 4 rows interleaved ----
    float mmax[4];
    int cnt[4];
    #pragma unroll
    for (int rr = 0; rr < 4; rr++) { mmax[rr] = -INFINITY; cnt[rr] = 0; }

    for (int rd = 0; rd < KNN; rd++) {
        float bs[4];
        #pragma unroll
        for (int rr = 0; rr < 4; rr++) bs[rr] = l0s[rr];
        #pragma unroll
        for (int st = 0; st < 6; st++) {
            const int off = 32 >> st;
            #pragma unroll
            for (int rr = 0; rr < 4; rr++)
                bs[rr] = fmaxf(bs[rr], __shfl_xor(bs[rr], off));
        }
        int bi[4];
        #pragma unroll
        for (int rr = 0; rr < 4; rr++) {
            unsigned long long mask = __ballot(l0s[rr] == bs[rr]);
            if (__popcll(mask) == 1) {
                int owner = __ffsll(mask) - 1;
                bi[rr] = __builtin_amdgcn_readlane(l0i[rr], owner);
            } else {
                // exact index tie-break among tied heads (rare)
                int cand = (l0s[rr] == bs[rr]) ? l0i[rr] : 0x7FFFFFFF;
                #pragma unroll
                for (int off = 32; off >= 1; off >>= 1)
                    cand = min(cand, __shfl_xor(cand, off));
                bi[rr] = cand;
            }
        }
        float4 p4[4];
        #pragma unroll
        for (int rr = 0; rr < 4; rr++) p4[rr] = pts[bi[rr]];
        #pragma unroll
        for (int rr = 0; rr < 4; rr++) {
            float dotp = wa0 * p4[rr].x + wa1 * p4[rr].y + wa2 * p4[rr].z;
            mmax[rr] = fmaxf(mmax[rr], dotp);
            bool own = (l0s[rr] == bs[rr]) && (l0i[rr] == bi[rr]);
            cnt[rr] += own ? 1 : 0;
            l0s[rr] = own ? l1s[rr] : l0s[rr]; l0i[rr] = own ? l1i[rr] : l0i[rr];
            l1s[rr] = own ? l2s[rr] : l1s[rr]; l1i[rr] = own ? l2i[rr] : l1i[rr];
            l2s[rr] = own ? l3s[rr] : l2s[rr]; l2i[rr] = own ? l3i[rr] : l2i[rr];
            l3s[rr] = own ? -INFINITY : l3s[rr];
            bool flag = own && (cnt[rr] == 4);   // lane exhausted its top-4
            if (__any(flag)) {
                // cold path (~1e-3/row): refill head with true next-best
                const float ps = bs[rr]; const int pm = bi[rr];
                float ns = -INFINITY; int ni = 0x7FFFFFFF;
                for (int j = 0; j < 64; j++) {
                    const int m = (j << 6) | lane;
                    const float4 p = pts[m];
                    float dot = __fadd_rn(__fadd_rn(__fmul_rn(q[rr].x, p.x),
                                                    __fmul_rn(q[rr].y, p.y)),
                                          __fmul_rn(q[rr].z, p.z));
                    float s = __fsub_rn(__fsub_rn(nq[rr], __fmul_rn(-2.0f, dot)), p.w);
                    bool worse = (s < ps) || (s == ps && m > pm);
                    bool bett  = (s > ns) || (s == ns && m < ni);
                    if (worse && bett) { ns = s; ni = m; }
                }
                if (flag) { l0s[rr] = ns; l0i[rr] = ni; cnt[rr] = 3; }
            }
        }
    }

    // conv = max_k(W0a.p_k) + (W0b-W0a).q ; (conv+b)*s+t ; lrelu.
    // s0>0 and lrelu monotone => max commutes past affine+activation.
    #pragma unroll
    for (int rr = 0; rr < 4; rr++) {
        float cterm = wd0 * q[rr].x + wd1 * q[rr].y + wd2 * q[rr].z;
        float z = (mmax[rr] + cterm + sB[lane]) * sS[lane] + sT[lane];
        H0[((size_t)(b * NPTS) + r0 + rr) * 64 + lane] = lrelu(z);
    }
}

// ---------------------------------------------------------------------------
// K2: pconv chain 64->64->128->128 + max over points.  256 blocks, each does
//     4 tiles of 32 points, amortizing the 149 KB weight staging.
// ---------------------------------------------------------------------------
__global__ __launch_bounds__(256) void k2_mlp(
        const float* __restrict__ H0,
        const float* __restrict__ W1, const float* __restrict__ b1,
        const float* __restrict__ s1, const float* __restrict__ t1,
        const float* __restrict__ W2, const float* __restrict__ b2,
        const float* __restrict__ s2, const float* __restrict__ t2,
        const float* __restrict__ W3, const float* __restrict__ b3,
        const float* __restrict__ s3, const float* __restrict__ t3,
        uint32_t* __restrict__ gmax)
{
    __shared__ float sW1[64 * 68];    // W1^T [c][o], stride 68
    __shared__ float sW2[64 * 132];   // W2^T [c][o], stride 132
    __shared__ float sW3[128 * 132];  // W3^T [c][o], stride 132
    __shared__ float h0t[32 * 65];
    __shared__ float h1t[32 * 65];
    __shared__ float h2t[32 * 129];
    __shared__ uint32_t bmax[128];

    const int t = threadIdx.x;
    const int blk = blockIdx.x;
    const int b = blk >> 5;               // 32 blocks per batch
    const int pbase0 = (blk & 31) * 128;  // 128 points per block

    for (int i = t; i < 64 * 64; i += 256)  { int o = i >> 6, c = i & 63;  sW1[c * 68 + o]  = W1[i]; }
    for (int i = t; i < 128 * 64; i += 256) { int o = i >> 6, c = i & 63;  sW2[c * 132 + o] = W2[i]; }
    for (int i = t; i < 128 * 128; i += 256){ int o = i >> 7, c = i & 127; sW3[c * 132 + o] = W3[i]; }
    if (t < 128) bmax[t] = 0u;
    __syncthreads();

    const int p = t >> 3;   // 0..31
    const int g = t & 7;

    for (int tile = 0; tile < 4; tile++) {
        const int pbase = pbase0 + tile * 32;
        {
            const float* src = &H0[((size_t)(b * NPTS) + pbase) * 64];
            for (int i = t; i < 32 * 64; i += 256) { int pp = i >> 6, c = i & 63; h0t[pp * 65 + c] = src[i]; }
        }
        __syncthreads();

        // L1: 64 -> 64, thread computes o = g*8 + [0..8)
        {
            float a[8];
            #pragma unroll
            for (int i = 0; i < 8; i++) a[i] = 0.f;
            const float* hrow = &h0t[p * 65];
            for (int c = 0; c < 64; c++) {
                float hv = hrow[c];
                const float4* wr = (const float4*)&sW1[c * 68 + g * 8];
                float4 w0v = wr[0], w1v = wr[1];
                a[0] += hv * w0v.x; a[1] += hv * w0v.y; a[2] += hv * w0v.z; a[3] += hv * w0v.w;
                a[4] += hv * w1v.x; a[5] += hv * w1v.y; a[6] += hv * w1v.z; a[7] += hv * w1v.w;
            }
            #pragma unroll
            for (int i = 0; i < 8; i++) {
                int o = g * 8 + i;
                float z = (a[i] + b1[o]) * s1[o] + t1[o];
                h1t[p * 65 + o] = lrelu(z);
            }
        }
        __syncthreads();

        // L2: 64 -> 128, thread computes o = g*16 + [0..16)
        {
            float a[16];
            #pragma unroll
            for (int i = 0; i < 16; i++) a[i] = 0.f;
            const float* hrow = &h1t[p * 65];
            for (int c = 0; c < 64; c++) {
                float hv = hrow[c];
                const float4* wr = (const float4*)&sW2[c * 132 + g * 16];
                #pragma unroll
                for (int v = 0; v < 4; v++) {
                    float4 wv = wr[v];
                    a[v * 4 + 0] += hv * wv.x; a[v * 4 + 1] += hv * wv.y;
                    a[v * 4 + 2] += hv * wv.z; a[v * 4 + 3] += hv * wv.w;
                }
            }
            #pragma unroll
            for (int i = 0; i < 16; i++) {
                int o = g * 16 + i;
                float z = (a[i] + b2[o]) * s2[o] + t2[o];
                h2t[p * 129 + o] = lrelu(z);
            }
        }
        __syncthreads();

        // L3: 128 -> 128 + block max
        {
            float a[16];
            #pragma unroll
            for (int i = 0; i < 16; i++) a[i] = 0.f;
            const float* hrow = &h2t[p * 129];
            for (int c = 0; c < 128; c++) {
                float hv = hrow[c];
                const float4* wr = (const float4*)&sW3[c * 132 + g * 16];
                #pragma unroll
                for (int v = 0; v < 4; v++) {
                    float4 wv = wr[v];
                    a[v * 4 + 0] += hv * wv.x; a[v * 4 + 1] += hv * wv.y;
                    a[v * 4 + 2] += hv * wv.z; a[v * 4 + 3] += hv * wv.w;
                }
            }
            #pragma unroll
            for (int i = 0; i < 16; i++) {
                int o = g * 16 + i;
                float z = (a[i] + b3[o]) * s3[o] + t3[o];
                atomicMax(&bmax[o], enc_f32(lrelu(z)));
            }
        }
        __syncthreads();
    }
    if (t < 128) atomicMax(&gmax[b * 128 + t], bmax[t]);
}

// ---------------------------------------------------------------------------
// K3: head 128 -> 512 (affine+lrelu) -> 1024.  64 blocks (8 batch x 8 chunk).
// ---------------------------------------------------------------------------
__global__ __launch_bounds__(256) void k3_head(
        const uint32_t* __restrict__ gmax,
        const float* __restrict__ W4, const float* __restrict__ b4,
        const float* __restrict__ s4, const float* __restrict__ t4,
        const float* __restrict__ W5, const float* __restrict__ b5,
        float* __restrict__ out)
{
    __shared__ float sIn[128];
    __shared__ float sH4[512];
    const int t = threadIdx.x;
    const int b = blockIdx.x >> 3;
    const int chunk = blockIdx.x & 7;

    if (t < 128) sIn[t] = dec_f32(gmax[b * 128 + t]);
    __syncthreads();

    #pragma unroll
    for (int rep = 0; rep < 2; rep++) {
        int o = t + rep * 256;
        const float4* wr = (const float4*)&W4[(size_t)o * 128];
        float acc = 0.f;
        for (int c4 = 0; c4 < 32; c4++) {
            float4 wv = wr[c4];
            acc += sIn[c4 * 4] * wv.x + sIn[c4 * 4 + 1] * wv.y
                 + sIn[c4 * 4 + 2] * wv.z + sIn[c4 * 4 + 3] * wv.w;
        }
        float z = (acc + b4[o]) * s4[o] + t4[o];
        sH4[o] = lrelu(z);
    }
    __syncthreads();

    if (t < 128) {
        int o = chunk * 128 + t;
        const float4* wr = (const float4*)&W5[(size_t)o * 512];
        float acc = 0.f;
        for (int c4 = 0; c4 < 128; c4++) {
            float4 wv = wr[c4];
            acc += sH4[c4 * 4] * wv.x + sH4[c4 * 4 + 1] * wv.y
                 + sH4[c4 * 4 + 2] * wv.z + sH4[c4 * 4 + 3] * wv.w;
        }
        out[(size_t)b * 1024 + o] = acc + b5[o];
    }
}

// ---------------------------------------------------------------------------
extern "C" void kernel_launch(void* const* d_in, const int* in_sizes, int n_in,
                              void* d_out, int out_size, void* d_ws, size_t ws_size,
                              hipStream_t stream) {
    (void)in_sizes; (void)n_in; (void)out_size; (void)ws_size;
    const float* x  = (const float*)d_in[0];
    const float* W0 = (const float*)d_in[1];
    const float* b0 = (const float*)d_in[2];
    const float* s0 = (const float*)d_in[3];
    const float* t0 = (const float*)d_in[4];
    const float* W1 = (const float*)d_in[5];
    const float* b1 = (const float*)d_in[6];
    const float* s1 = (const float*)d_in[7];
    const float* t1 = (const float*)d_in[8];
    const float* W2 = (const float*)d_in[9];
    const float* b2 = (const float*)d_in[10];
    const float* s2 = (const float*)d_in[11];
    const float* t2 = (const float*)d_in[12];
    const float* W3 = (const float*)d_in[13];
    const float* b3 = (const float*)d_in[14];
    const float* s3 = (const float*)d_in[15];
    const float* t3 = (const float*)d_in[16];
    const float* W4 = (const float*)d_in[17];
    const float* b4 = (const float*)d_in[18];
    const float* s4 = (const float*)d_in[19];
    const float* t4 = (const float*)d_in[20];
    const float* W5 = (const float*)d_in[21];
    const float* b5 = (const float*)d_in[22];

    float* H0 = (float*)d_ws;                                  // [8][4096][64] f32 = 8 MB
    uint32_t* gmax = (uint32_t*)((char*)d_ws + (size_t)NB * NPTS * 64 * 4);  // [8][128] u32

    hipMemsetAsync(gmax, 0, NB * 128 * sizeof(uint32_t), stream);  // enc(-inf) floor

    k1_knn_edge<<<dim3(1024), dim3(512), 0, stream>>>(x, W0, b0, s0, t0, H0);
    k2_mlp<<<dim3(256), dim3(256), 0, stream>>>(H0, W1, b1, s1, t1,
                                                W2, b2, s2, t2,
                                                W3, b3, s3, t3, gmax);
    k3_head<<<dim3(64), dim3(256), 0, stream>>>(gmax, W4, b4, s4, t4, W5, b5,
                                                (float*)d_out);
}